// Round 3
// baseline (404.091 us; speedup 1.0000x reference)
//
#include <hip/hip_runtime.h>
#include <hip/hip_bf16.h>

// QuantizedLinear: out[n][o] = scale[o] * dot(x[n,:], (q[o,:]-8)) + bias[o]
// R3: switch GEMM to mfma_f32_32x32x16_bf16 (half the MFMA issue slots,
// -17% matrix-pipe cycles vs 16x16x32 per m119) with K-MAJOR LDS layout
// [kblock][row]: fragment ds_read_b128 are lane-contiguous (conflict-free)
// and ALL read offsets are compile-time immediates (no frag-addr VALU in
// the K-loop). Staging global_load_lds becomes a per-lane 16B row-gather;
// every 128B line is fully consumed within the same tile iteration.
// Prep (x->bf16, nibble->bf16) merged into one kernel.

typedef __attribute__((ext_vector_type(8))) __bf16 bf16x8;
typedef __attribute__((ext_vector_type(16))) float f32x16;

#define GLOBAL_AS __attribute__((address_space(1)))
#define LDS_AS __attribute__((address_space(3)))

#define BM 128
#define BN 128
#define BK 64

__device__ inline unsigned short f32_to_bf16(float f) {
    unsigned int u = __float_as_uint(f);
    unsigned int r = (u + 0x7FFFu + ((u >> 16) & 1u)) >> 16;
    return (unsigned short)r;
}

// ---- merged preprocessing: x fp32 -> bf16 AND packed nibbles -> bf16 ints ----
// work items [0, n8x): convert 8 floats each; [n8x, n8x+n4w): unpack 4 int32 each.
__global__ void prep(const float* __restrict__ x, unsigned short* __restrict__ xb,
                     const int* __restrict__ wp, unsigned short* __restrict__ wb,
                     int n8x, int n4w) {
    const int stride = gridDim.x * blockDim.x;
    const int total = n8x + n4w;
    for (int i = blockIdx.x * blockDim.x + threadIdx.x; i < total; i += stride) {
        if (i < n8x) {
            float4 a = ((const float4*)x)[2 * i];
            float4 b = ((const float4*)x)[2 * i + 1];
            union { unsigned short h[8]; uint4 u; } o;
            o.h[0] = f32_to_bf16(a.x); o.h[1] = f32_to_bf16(a.y);
            o.h[2] = f32_to_bf16(a.z); o.h[3] = f32_to_bf16(a.w);
            o.h[4] = f32_to_bf16(b.x); o.h[5] = f32_to_bf16(b.y);
            o.h[6] = f32_to_bf16(b.z); o.h[7] = f32_to_bf16(b.w);
            ((uint4*)xb)[i] = o.u;
        } else {
            int k = i - n8x;
            int4 v = ((const int4*)wp)[k];
            int vals[4] = {v.x, v.y, v.z, v.w};
            union { unsigned short h[8]; uint4 u; } o;
#pragma unroll
            for (int t = 0; t < 4; ++t) {
                o.h[2 * t]     = f32_to_bf16((float)((vals[t] & 0xF) - 8));
                o.h[2 * t + 1] = f32_to_bf16((float)(((vals[t] >> 4) & 0xF) - 8));
            }
            ((uint4*)wb)[k] = o.u;
        }
    }
}

// ---- main GEMM: C[m][n] = sum_k A[m][k]*B[n][k]; epilogue scale/bias ----
// LDS is k-major: tile slot (kb, row) at shorts offset kb*1024 + row*8,
// kb in [0,8) (8-elem k-blocks of BK=64), row in [0,128).
__global__ __launch_bounds__(256) void gemm_bt(
    const unsigned short* __restrict__ A,
    const unsigned short* __restrict__ B,
    const float* __restrict__ scales,
    const float* __restrict__ bias,
    float* __restrict__ C,
    int M, int N, int K)
{
    __shared__ unsigned short As[BM * BK];  // 16 KB, k-major
    __shared__ unsigned short Bs[BN * BK];  // 16 KB, k-major

    const int tid  = threadIdx.x;
    const int wave = tid >> 6;
    const int lane = tid & 63;
    const int wm = wave >> 1;
    const int wn = wave & 1;
    const int m0 = blockIdx.y * BM;
    const int n0 = blockIdx.x * BN;

    f32x16 acc[2][2];
#pragma unroll
    for (int i = 0; i < 2; ++i)
#pragma unroll
        for (int j = 0; j < 2; ++j)
#pragma unroll
            for (int r = 0; r < 16; ++r)
                acc[i][j][r] = 0.f;

    // staging decode: call j, thread tid fills slot s = j*256+tid
    //   -> kb = s>>7 = 2*j + (tid>>7), row = s&127 = tid&127
    const int srow = tid & 127;
    const int kbb  = tid >> 7;            // 0 or 1

    const unsigned short* Ag = A + (size_t)(m0 + srow) * K + kbb * 8;
    const unsigned short* Bg = B + (size_t)(n0 + srow) * K + kbb * 8;

    // fragment read bases (k-major, everything else is an immediate):
    // addr_shorts = (2*ki + half)*1024 + (w*64 + t*32 + lanelow)*8
    const int lanelow = lane & 31;
    const int half    = lane >> 5;
    const int aoff = half * 1024 + (wm * 64 + lanelow) * 8;
    const int boff = half * 1024 + (wn * 64 + lanelow) * 8;

    for (int k0 = 0; k0 < K; k0 += BK) {
#pragma unroll
        for (int j = 0; j < 4; ++j) {
            __builtin_amdgcn_global_load_lds(
                (const GLOBAL_AS void*)(Ag + k0 + j * 16),
                (LDS_AS void*)((LDS_AS char*)As + tid * 16 + j * 4096), 16, 0, 0);
        }
#pragma unroll
        for (int j = 0; j < 4; ++j) {
            __builtin_amdgcn_global_load_lds(
                (const GLOBAL_AS void*)(Bg + k0 + j * 16),
                (LDS_AS void*)((LDS_AS char*)Bs + tid * 16 + j * 4096), 16, 0, 0);
        }
        __syncthreads();

#pragma unroll
        for (int ki = 0; ki < 4; ++ki) {
            bf16x8 af[2], bfr[2];
#pragma unroll
            for (int t = 0; t < 2; ++t)
                af[t] = *(const bf16x8*)&As[aoff + ki * 2048 + t * 256];
#pragma unroll
            for (int t = 0; t < 2; ++t)
                bfr[t] = *(const bf16x8*)&Bs[boff + ki * 2048 + t * 256];
#pragma unroll
            for (int i = 0; i < 2; ++i)
#pragma unroll
                for (int j = 0; j < 2; ++j)
                    acc[i][j] = __builtin_amdgcn_mfma_f32_32x32x16_bf16(af[i], bfr[j], acc[i][j], 0, 0, 0);
        }
        __syncthreads();
    }

    // epilogue: 32x32 C/D layout col=lane&31, row=(reg&3)+8*(reg>>2)+4*(lane>>5)
#pragma unroll
    for (int tj = 0; tj < 2; ++tj) {
        const int col = n0 + wn * 64 + tj * 32 + lanelow;
        const float s = scales[col];
        const float b = bias[col];
#pragma unroll
        for (int ti = 0; ti < 2; ++ti) {
            const int rowbase = m0 + wm * 64 + ti * 32 + half * 4;
#pragma unroll
            for (int r = 0; r < 16; ++r) {
                const int row = rowbase + (r & 3) + 8 * (r >> 2);
                C[(size_t)row * N + col] = acc[ti][tj][r] * s + b;
            }
        }
    }
}

// ---- correctness fallback if workspace is too small ----
__global__ void naive_kernel(const float* __restrict__ x, const int* __restrict__ wp,
                             const float* __restrict__ sc, const float* __restrict__ bs,
                             float* __restrict__ out, int NR, int OUTF, int INF) {
    int idx = blockIdx.x * 256 + threadIdx.x;
    if (idx >= NR * OUTF) return;
    int n = idx / OUTF, o = idx - n * OUTF;
    const float* xr = x + (size_t)n * INF;
    const int* wr = wp + (size_t)o * (INF / 2);
    float acc = 0.f;
    for (int c = 0; c < INF / 2; ++c) {
        int v = wr[c];
        acc += xr[2 * c] * (float)((v & 0xF) - 8) + xr[2 * c + 1] * (float)(((v >> 4) & 0xF) - 8);
    }
    out[idx] = acc * sc[o] + bs[o];
}

extern "C" void kernel_launch(void* const* d_in, const int* in_sizes, int n_in,
                              void* d_out, int out_size, void* d_ws, size_t ws_size,
                              hipStream_t stream) {
    const float* x      = (const float*)d_in[0];
    const int*   wp     = (const int*)d_in[1];
    const float* scales = (const float*)d_in[2];
    const float* bias   = (const float*)d_in[3];
    float* out = (float*)d_out;

    const int OUTF = in_sizes[2];
    const int INF  = (2 * in_sizes[1]) / OUTF;
    const int NR   = in_sizes[0] / INF;

    unsigned short* xb = (unsigned short*)d_ws;
    unsigned short* wb = xb + (size_t)NR * INF;
    const size_t need = ((size_t)NR * INF + (size_t)OUTF * INF) * sizeof(unsigned short);

    if (ws_size >= need && (NR % BM) == 0 && (OUTF % BN) == 0 && (INF % BK) == 0
        && (in_sizes[0] % 8) == 0 && (in_sizes[1] % 4) == 0) {
        prep<<<1024, 256, 0, stream>>>(x, xb, wp, wb, in_sizes[0] / 8, in_sizes[1] / 4);
        dim3 grid(OUTF / BN, NR / BM);
        gemm_bt<<<grid, 256, 0, stream>>>(xb, wb, scales, bias, out, NR, OUTF, INF);
    } else {
        int total = NR * OUTF;
        naive_kernel<<<(total + 255) / 256, 256, 0, stream>>>(x, wp, scales, bias, out, NR, OUTF, INF);
    }
}

// Round 4
// 316.133 us; speedup vs baseline: 1.2782x; 1.2782x over previous
//
#include <hip/hip_runtime.h>
#include <hip/hip_bf16.h>

// QuantizedLinear: out[n][o] = scale[o] * dot(x[n,:], (q[o,:]-8)) + bias[o]
// R4 = R2 (best measured: row-major LDS + XOR swizzle, 16x16x32 MFMA)
//    + explicitly hoisted fragment LDS addresses. R2's swizzle pushed
//    VALUBusy 25->43% because the compiler re-derived the (loop-invariant)
//    swizzled addresses every kk. We precompute 4 A + 4 B byte offsets once;
//    the kk=32 address is offset^64 (aq+4 == aq^4 for aq<4). K-loop body is
//    now ds_read(imm-held offs) + XOR + MFMA + staging only.
// R3's k-major staging (per-lane row gather) was TA request-rate bound
// (VALUBusy 6%, dur +54%) — reverted.

typedef __attribute__((ext_vector_type(8))) __bf16 bf16x8;
typedef __attribute__((ext_vector_type(4))) float f32x4;

#define GLOBAL_AS __attribute__((address_space(1)))
#define LDS_AS __attribute__((address_space(3)))

#define BM 128
#define BN 128
#define BK 64

__device__ inline unsigned short f32_to_bf16(float f) {
    unsigned int u = __float_as_uint(f);
    unsigned int r = (u + 0x7FFFu + ((u >> 16) & 1u)) >> 16;
    return (unsigned short)r;
}

// ---- merged preprocessing: x fp32 -> bf16 AND packed nibbles -> bf16 ints ----
__global__ void prep(const float* __restrict__ x, unsigned short* __restrict__ xb,
                     const int* __restrict__ wp, unsigned short* __restrict__ wb,
                     int n8x, int n4w) {
    const int stride = gridDim.x * blockDim.x;
    const int total = n8x + n4w;
    for (int i = blockIdx.x * blockDim.x + threadIdx.x; i < total; i += stride) {
        if (i < n8x) {
            float4 a = ((const float4*)x)[2 * i];
            float4 b = ((const float4*)x)[2 * i + 1];
            union { unsigned short h[8]; uint4 u; } o;
            o.h[0] = f32_to_bf16(a.x); o.h[1] = f32_to_bf16(a.y);
            o.h[2] = f32_to_bf16(a.z); o.h[3] = f32_to_bf16(a.w);
            o.h[4] = f32_to_bf16(b.x); o.h[5] = f32_to_bf16(b.y);
            o.h[6] = f32_to_bf16(b.z); o.h[7] = f32_to_bf16(b.w);
            ((uint4*)xb)[i] = o.u;
        } else {
            int k = i - n8x;
            int4 v = ((const int4*)wp)[k];
            int vals[4] = {v.x, v.y, v.z, v.w};
            union { unsigned short h[8]; uint4 u; } o;
#pragma unroll
            for (int t = 0; t < 4; ++t) {
                o.h[2 * t]     = f32_to_bf16((float)((vals[t] & 0xF) - 8));
                o.h[2 * t + 1] = f32_to_bf16((float)(((vals[t] >> 4) & 0xF) - 8));
            }
            ((uint4*)wb)[k] = o.u;
        }
    }
}

// ---- main GEMM: C[m][n] = sum_k A[m][k]*B[n][k]; epilogue scale/bias ----
__global__ __launch_bounds__(256) void gemm_bt(
    const unsigned short* __restrict__ A,
    const unsigned short* __restrict__ B,
    const float* __restrict__ scales,
    const float* __restrict__ bias,
    float* __restrict__ C,
    int M, int N, int K)
{
    __shared__ unsigned short As[BM * BK];  // 16 KB
    __shared__ unsigned short Bs[BN * BK];  // 16 KB

    const int tid  = threadIdx.x;
    const int wave = tid >> 6;
    const int lane = tid & 63;
    const int wm = wave >> 1;
    const int wn = wave & 1;
    const int m0 = blockIdx.y * BM;
    const int n0 = blockIdx.x * BN;

    f32x4 acc[4][4];
#pragma unroll
    for (int i = 0; i < 4; ++i)
#pragma unroll
        for (int j = 0; j < 4; ++j)
            acc[i][j] = (f32x4){0.f, 0.f, 0.f, 0.f};

    // staging: thread tid loads 16B landing at LDS slot (row = tid>>3 (+32j),
    // kb = tid&7). XOR-swizzle: that slot holds global k-block kb ^ (row&7).
    const int srow = tid >> 3;
    const int scol = ((tid & 7) ^ (srow & 7)) * 8;

    const unsigned short* Ag = A + (size_t)(m0 + srow) * K + scol;
    const unsigned short* Bg = B + (size_t)(n0 + srow) * K + scol;

    // fragment addressing (hoisted): lane reads row (am) of its 16-tile at
    // swizzled chunk (aq ^ (am&7)). Byte offset within As/Bs; kk=32 is ^64.
    const int am = lane & 15;
    const int aq = lane >> 4;
    const int cbyte = ((aq ^ (am & 7)) << 4);   // chunk * 16 bytes

    int aoffB[4], boffB[4];
#pragma unroll
    for (int i = 0; i < 4; ++i)
        aoffB[i] = (wm * 64 + i * 16 + am) * (BK * 2) + cbyte;
#pragma unroll
    for (int j = 0; j < 4; ++j)
        boffB[j] = (wn * 64 + j * 16 + am) * (BK * 2) + cbyte;

    const char* AsB = (const char*)As;
    const char* BsB = (const char*)Bs;

    for (int k0 = 0; k0 < K; k0 += BK) {
#pragma unroll
        for (int j = 0; j < 4; ++j) {
            __builtin_amdgcn_global_load_lds(
                (const GLOBAL_AS void*)(Ag + (size_t)(j * 32) * K + k0),
                (LDS_AS void*)(As + tid * 8 + j * 2048), 16, 0, 0);
        }
#pragma unroll
        for (int j = 0; j < 4; ++j) {
            __builtin_amdgcn_global_load_lds(
                (const GLOBAL_AS void*)(Bg + (size_t)(j * 32) * K + k0),
                (LDS_AS void*)(Bs + tid * 8 + j * 2048), 16, 0, 0);
        }
        __syncthreads();

        {   // kk = 0
            bf16x8 af[4], bfr[4];
#pragma unroll
            for (int i = 0; i < 4; ++i) af[i] = *(const bf16x8*)(AsB + aoffB[i]);
#pragma unroll
            for (int j = 0; j < 4; ++j) bfr[j] = *(const bf16x8*)(BsB + boffB[j]);
#pragma unroll
            for (int i = 0; i < 4; ++i)
#pragma unroll
                for (int j = 0; j < 4; ++j)
                    acc[i][j] = __builtin_amdgcn_mfma_f32_16x16x32_bf16(af[i], bfr[j], acc[i][j], 0, 0, 0);
        }
        {   // kk = 32  (chunk ^ 4  ->  byte offset ^ 64)
            bf16x8 af[4], bfr[4];
#pragma unroll
            for (int i = 0; i < 4; ++i) af[i] = *(const bf16x8*)(AsB + (aoffB[i] ^ 64));
#pragma unroll
            for (int j = 0; j < 4; ++j) bfr[j] = *(const bf16x8*)(BsB + (boffB[j] ^ 64));
#pragma unroll
            for (int i = 0; i < 4; ++i)
#pragma unroll
                for (int j = 0; j < 4; ++j)
                    acc[i][j] = __builtin_amdgcn_mfma_f32_16x16x32_bf16(af[i], bfr[j], acc[i][j], 0, 0, 0);
        }
        __syncthreads();
    }

    // epilogue: C/D layout col=lane&15, row=(lane>>4)*4+reg
    const int cq = lane >> 4;
    const int cc = lane & 15;
#pragma unroll
    for (int j = 0; j < 4; ++j) {
        const int col = n0 + wn * 64 + j * 16 + cc;
        const float s = scales[col];
        const float b = bias[col];
#pragma unroll
        for (int i = 0; i < 4; ++i) {
            const int rowb = m0 + wm * 64 + i * 16 + cq * 4;
#pragma unroll
            for (int r = 0; r < 4; ++r) {
                C[(size_t)(rowb + r) * N + col] = acc[i][j][r] * s + b;
            }
        }
    }
}

// ---- correctness fallback if workspace is too small ----
__global__ void naive_kernel(const float* __restrict__ x, const int* __restrict__ wp,
                             const float* __restrict__ sc, const float* __restrict__ bs,
                             float* __restrict__ out, int NR, int OUTF, int INF) {
    int idx = blockIdx.x * 256 + threadIdx.x;
    if (idx >= NR * OUTF) return;
    int n = idx / OUTF, o = idx - n * OUTF;
    const float* xr = x + (size_t)n * INF;
    const int* wr = wp + (size_t)o * (INF / 2);
    float acc = 0.f;
    for (int c = 0; c < INF / 2; ++c) {
        int v = wr[c];
        acc += xr[2 * c] * (float)((v & 0xF) - 8) + xr[2 * c + 1] * (float)(((v >> 4) & 0xF) - 8);
    }
    out[idx] = acc * sc[o] + bs[o];
}

extern "C" void kernel_launch(void* const* d_in, const int* in_sizes, int n_in,
                              void* d_out, int out_size, void* d_ws, size_t ws_size,
                              hipStream_t stream) {
    const float* x      = (const float*)d_in[0];
    const int*   wp     = (const int*)d_in[1];
    const float* scales = (const float*)d_in[2];
    const float* bias   = (const float*)d_in[3];
    float* out = (float*)d_out;

    const int OUTF = in_sizes[2];
    const int INF  = (2 * in_sizes[1]) / OUTF;
    const int NR   = in_sizes[0] / INF;

    unsigned short* xb = (unsigned short*)d_ws;
    unsigned short* wb = xb + (size_t)NR * INF;
    const size_t need = ((size_t)NR * INF + (size_t)OUTF * INF) * sizeof(unsigned short);

    if (ws_size >= need && (NR % BM) == 0 && (OUTF % BN) == 0 && (INF % BK) == 0
        && (in_sizes[0] % 8) == 0 && (in_sizes[1] % 4) == 0) {
        prep<<<1024, 256, 0, stream>>>(x, xb, wp, wb, in_sizes[0] / 8, in_sizes[1] / 4);
        dim3 grid(OUTF / BN, NR / BM);
        gemm_bt<<<grid, 256, 0, stream>>>(xb, wb, scales, bias, out, NR, OUTF, INF);
    } else {
        int total = NR * OUTF;
        naive_kernel<<<(total + 255) / 256, 256, 0, stream>>>(x, wp, scales, bias, out, NR, OUTF, INF);
    }
}

// Round 5
// 292.383 us; speedup vs baseline: 1.3821x; 1.0812x over previous
//
#include <hip/hip_runtime.h>
#include <hip/hip_bf16.h>

// QuantizedLinear: out[n][o] = scale[o] * dot(x[n,:], (q[o,:]-8)) + bias[o]
// R5 = R4 + (a) compile-time K,N via template (all staging offsets j*32*K and
// C row strides become immediates/shifts — m97-class kernels hardcode dims),
// (b) XCD-aware 4x2 supertile block swizzle: 8 consecutive block ids (one
// round-robin pass over the 8 XCDs) cover a 4x2 tile of the block grid, so
// co-dispatched blocks share A/B panels in their XCD L2s (FETCH 164->~115MB).
// Kept: row-major LDS + XOR swizzle (conflicts=0), 16x16x32 bf16 MFMA,
// hoisted fragment addrs, fused scale/bias epilogue.

typedef __attribute__((ext_vector_type(8))) __bf16 bf16x8;
typedef __attribute__((ext_vector_type(4))) float f32x4;

#define GLOBAL_AS __attribute__((address_space(1)))
#define LDS_AS __attribute__((address_space(3)))

#define BM 128
#define BN 128
#define BK 64

__device__ inline unsigned short f32_to_bf16(float f) {
    unsigned int u = __float_as_uint(f);
    unsigned int r = (u + 0x7FFFu + ((u >> 16) & 1u)) >> 16;
    return (unsigned short)r;
}

// ---- merged preprocessing: x fp32 -> bf16 AND packed nibbles -> bf16 ints ----
__global__ void prep(const float* __restrict__ x, unsigned short* __restrict__ xb,
                     const int* __restrict__ wp, unsigned short* __restrict__ wb,
                     int n8x, int n4w) {
    const int stride = gridDim.x * blockDim.x;
    const int total = n8x + n4w;
    for (int i = blockIdx.x * blockDim.x + threadIdx.x; i < total; i += stride) {
        if (i < n8x) {
            float4 a = ((const float4*)x)[2 * i];
            float4 b = ((const float4*)x)[2 * i + 1];
            union { unsigned short h[8]; uint4 u; } o;
            o.h[0] = f32_to_bf16(a.x); o.h[1] = f32_to_bf16(a.y);
            o.h[2] = f32_to_bf16(a.z); o.h[3] = f32_to_bf16(a.w);
            o.h[4] = f32_to_bf16(b.x); o.h[5] = f32_to_bf16(b.y);
            o.h[6] = f32_to_bf16(b.z); o.h[7] = f32_to_bf16(b.w);
            ((uint4*)xb)[i] = o.u;
        } else {
            int k = i - n8x;
            int4 v = ((const int4*)wp)[k];
            int vals[4] = {v.x, v.y, v.z, v.w};
            union { unsigned short h[8]; uint4 u; } o;
#pragma unroll
            for (int t = 0; t < 4; ++t) {
                o.h[2 * t]     = f32_to_bf16((float)((vals[t] & 0xF) - 8));
                o.h[2 * t + 1] = f32_to_bf16((float)(((vals[t] >> 4) & 0xF) - 8));
            }
            ((uint4*)wb)[k] = o.u;
        }
    }
}

// ---- main GEMM: C[m][n] = sum_k A[m][k]*B[n][k]; epilogue scale/bias ----
// K, N compile-time. Grid is 1-D; block ids are remapped in 4x2 supertiles
// (gx supertiles fastest) so each round of 8 XCD-round-robin blocks shares
// a 2-row x 4-col panel footprint.
template<int K, int N>
__global__ __launch_bounds__(256) void gemm_bt(
    const unsigned short* __restrict__ A,
    const unsigned short* __restrict__ B,
    const float* __restrict__ scales,
    const float* __restrict__ bias,
    float* __restrict__ C,
    int GX)   // blocks along N; GY implied by gridDim.x / GX
{
    __shared__ unsigned short As[BM * BK];  // 16 KB
    __shared__ unsigned short Bs[BN * BK];  // 16 KB

    const int tid  = threadIdx.x;
    const int wave = tid >> 6;
    const int lane = tid & 63;
    const int wm = wave >> 1;
    const int wn = wave & 1;

    // XCD-aware supertile swizzle: groups of 8 ids -> 4x2 (x,y) tile.
    const int bid = blockIdx.x;
    const int g   = bid >> 3;
    const int t8  = bid & 7;
    const int sgx = GX >> 2;                 // supertiles along x
    const int bx  = (g % sgx) * 4 + (t8 & 3);
    const int by  = (g / sgx) * 2 + (t8 >> 2);
    const int m0 = by * BM;
    const int n0 = bx * BN;

    f32x4 acc[4][4];
#pragma unroll
    for (int i = 0; i < 4; ++i)
#pragma unroll
        for (int j = 0; j < 4; ++j)
            acc[i][j] = (f32x4){0.f, 0.f, 0.f, 0.f};

    // staging: thread tid loads 16B landing at LDS slot (row = tid>>3 (+32j),
    // kb = tid&7). XOR-swizzle: that slot holds global k-block kb ^ (row&7).
    const int srow = tid >> 3;
    const int scol = ((tid & 7) ^ (srow & 7)) * 8;

    const unsigned short* Ag = A + (size_t)(m0 + srow) * K + scol;
    const unsigned short* Bg = B + (size_t)(n0 + srow) * K + scol;

    // fragment addressing (hoisted): lane reads row (am) at swizzled chunk
    // (aq ^ (am&7)); kk=32 is byte-offset ^64.
    const int am = lane & 15;
    const int aq = lane >> 4;
    const int cbyte = ((aq ^ (am & 7)) << 4);

    int aoffB[4], boffB[4];
#pragma unroll
    for (int i = 0; i < 4; ++i)
        aoffB[i] = (wm * 64 + i * 16 + am) * (BK * 2) + cbyte;
#pragma unroll
    for (int j = 0; j < 4; ++j)
        boffB[j] = (wn * 64 + j * 16 + am) * (BK * 2) + cbyte;

    const char* AsB = (const char*)As;
    const char* BsB = (const char*)Bs;

    for (int k0 = 0; k0 < K; k0 += BK) {
#pragma unroll
        for (int j = 0; j < 4; ++j) {
            __builtin_amdgcn_global_load_lds(
                (const GLOBAL_AS void*)(Ag + (size_t)(j * 32) * K + k0),
                (LDS_AS void*)(As + tid * 8 + j * 2048), 16, 0, 0);
        }
#pragma unroll
        for (int j = 0; j < 4; ++j) {
            __builtin_amdgcn_global_load_lds(
                (const GLOBAL_AS void*)(Bg + (size_t)(j * 32) * K + k0),
                (LDS_AS void*)(Bs + tid * 8 + j * 2048), 16, 0, 0);
        }
        __syncthreads();

        {   // kk = 0
            bf16x8 af[4], bfr[4];
#pragma unroll
            for (int i = 0; i < 4; ++i) af[i] = *(const bf16x8*)(AsB + aoffB[i]);
#pragma unroll
            for (int j = 0; j < 4; ++j) bfr[j] = *(const bf16x8*)(BsB + boffB[j]);
#pragma unroll
            for (int i = 0; i < 4; ++i)
#pragma unroll
                for (int j = 0; j < 4; ++j)
                    acc[i][j] = __builtin_amdgcn_mfma_f32_16x16x32_bf16(af[i], bfr[j], acc[i][j], 0, 0, 0);
        }
        {   // kk = 32
            bf16x8 af[4], bfr[4];
#pragma unroll
            for (int i = 0; i < 4; ++i) af[i] = *(const bf16x8*)(AsB + (aoffB[i] ^ 64));
#pragma unroll
            for (int j = 0; j < 4; ++j) bfr[j] = *(const bf16x8*)(BsB + (boffB[j] ^ 64));
#pragma unroll
            for (int i = 0; i < 4; ++i)
#pragma unroll
                for (int j = 0; j < 4; ++j)
                    acc[i][j] = __builtin_amdgcn_mfma_f32_16x16x32_bf16(af[i], bfr[j], acc[i][j], 0, 0, 0);
        }
        __syncthreads();
    }

    // epilogue: C/D layout col=lane&15, row=(lane>>4)*4+reg
    const int cq = lane >> 4;
    const int cc = lane & 15;
#pragma unroll
    for (int j = 0; j < 4; ++j) {
        const int col = n0 + wn * 64 + j * 16 + cc;
        const float s = scales[col];
        const float b = bias[col];
#pragma unroll
        for (int i = 0; i < 4; ++i) {
            const int rowb = m0 + wm * 64 + i * 16 + cq * 4;
#pragma unroll
            for (int r = 0; r < 4; ++r) {
                C[(size_t)(rowb + r) * N + col] = acc[i][j][r] * s + b;
            }
        }
    }
}

// ---- correctness fallback for unexpected shapes ----
__global__ void naive_kernel(const float* __restrict__ x, const int* __restrict__ wp,
                             const float* __restrict__ sc, const float* __restrict__ bs,
                             float* __restrict__ out, int NR, int OUTF, int INF) {
    int idx = blockIdx.x * 256 + threadIdx.x;
    if (idx >= NR * OUTF) return;
    int n = idx / OUTF, o = idx - n * OUTF;
    const float* xr = x + (size_t)n * INF;
    const int* wr = wp + (size_t)o * (INF / 2);
    float acc = 0.f;
    for (int c = 0; c < INF / 2; ++c) {
        int v = wr[c];
        acc += xr[2 * c] * (float)((v & 0xF) - 8) + xr[2 * c + 1] * (float)(((v >> 4) & 0xF) - 8);
    }
    out[idx] = acc * sc[o] + bs[o];
}

extern "C" void kernel_launch(void* const* d_in, const int* in_sizes, int n_in,
                              void* d_out, int out_size, void* d_ws, size_t ws_size,
                              hipStream_t stream) {
    const float* x      = (const float*)d_in[0];
    const int*   wp     = (const int*)d_in[1];
    const float* scales = (const float*)d_in[2];
    const float* bias   = (const float*)d_in[3];
    float* out = (float*)d_out;

    const int OUTF = in_sizes[2];
    const int INF  = (2 * in_sizes[1]) / OUTF;
    const int NR   = in_sizes[0] / INF;

    unsigned short* xb = (unsigned short*)d_ws;
    unsigned short* wb = xb + (size_t)NR * INF;
    const size_t need = ((size_t)NR * INF + (size_t)OUTF * INF) * sizeof(unsigned short);

    if (ws_size >= need && INF == 4096 && OUTF == 4096 && (NR % BM) == 0
        && (in_sizes[0] % 8) == 0 && (in_sizes[1] % 4) == 0) {
        prep<<<2048, 256, 0, stream>>>(x, xb, wp, wb, in_sizes[0] / 8, in_sizes[1] / 4);
        const int GX = OUTF / BN;           // 32
        const int GY = NR / BM;
        gemm_bt<4096, 4096><<<GX * GY, 256, 0, stream>>>(xb, wb, scales, bias, out, GX);
    } else {
        int total = NR * OUTF;
        naive_kernel<<<(total + 255) / 256, 256, 0, stream>>>(x, wp, scales, bias, out, NR, OUTF, INF);
    }
}